// Round 4
// baseline (861.949 us; speedup 1.0000x reference)
//
#include <hip/hip_runtime.h>

// MPNN, 3 layers, N=50000, E=800000, D=64, fp32.
//   hx[d] = x[d] + sum_{e: dst=d} x[src_e]            (CSR gather kernel)
//   out   = relu(hx@W1 + x@W2 + bu + (deg+1)*dvec)    (streaming GEMM kernel)
// W1 = Wm @ Wu_top, W2 = Wu_bot, dvec = bm @ Wu_top   (precomputed once)
// Split kernels: gather is latency-bound -> lean regs, 8 waves/SIMD;
// GEMM holds weights in registers -> issue-bound streaming, prefetched.

#define DIM 64

__global__ __launch_bounds__(256) void fuse_weights_kernel(
    const float* __restrict__ Wm0, const float* __restrict__ bm0, const float* __restrict__ Wu0,
    const float* __restrict__ Wm1, const float* __restrict__ bm1, const float* __restrict__ Wu1,
    const float* __restrict__ Wm2, const float* __restrict__ bm2, const float* __restrict__ Wu2,
    float* __restrict__ W1, float* __restrict__ dv) {
  const int l = blockIdx.x;
  const float* Wm = l == 0 ? Wm0 : l == 1 ? Wm1 : Wm2;
  const float* bm = l == 0 ? bm0 : l == 1 ? bm1 : bm2;
  const float* Wu = l == 0 ? Wu0 : l == 1 ? Wu1 : Wu2;
  float* W1l = W1 + l * 4096;
  float* dvl = dv + l * 64;
  __shared__ float sWm[64 * 64];
  __shared__ float sWu[64 * 64];  // top half of Wu (rows 0..63)
  const int tid = threadIdx.x;
  for (int i = tid; i < 4096; i += 256) {
    sWm[i] = Wm[i];
    sWu[i] = Wu[i];
  }
  __syncthreads();
  for (int i = tid; i < 4096; i += 256) {
    const int r = i >> 6, c = i & 63;
    float acc = 0.f;
#pragma unroll
    for (int k = 0; k < 64; ++k) acc = fmaf(sWm[r * 64 + k], sWu[k * 64 + c], acc);
    W1l[i] = acc;
  }
  if (tid < 64) {
    float acc = 0.f;
#pragma unroll
    for (int k = 0; k < 64; ++k) acc = fmaf(bm[k], sWu[k * 64 + tid], acc);
    dvl[tid] = acc;
  }
}

__global__ __launch_bounds__(256) void deg_kernel(const int* __restrict__ dst,
                                                  int* __restrict__ deg, int E) {
  const int e = blockIdx.x * 256 + threadIdx.x;
  if (e < E) atomicAdd(&deg[dst[e]], 1);
}

// 3-phase multi-block exclusive scan of deg -> rowptr
__global__ __launch_bounds__(256) void scan_sum_kernel(const int* __restrict__ deg,
                                                       int* __restrict__ bsum, int n) {
  const int i = blockIdx.x * 256 + threadIdx.x;
  int v = (i < n) ? deg[i] : 0;
#pragma unroll
  for (int off = 1; off < 64; off <<= 1) v += __shfl_down(v, off, 64);
  __shared__ int ws[4];
  if ((threadIdx.x & 63) == 0) ws[threadIdx.x >> 6] = v;
  __syncthreads();
  if (threadIdx.x == 0) bsum[blockIdx.x] = ws[0] + ws[1] + ws[2] + ws[3];
}

__global__ __launch_bounds__(256) void scan_block_kernel(const int* __restrict__ bsum,
                                                         int* __restrict__ boff, int nb) {
  __shared__ int s[256];
  const int t = threadIdx.x;
  s[t] = (t < nb) ? bsum[t] : 0;
  __syncthreads();
  for (int off = 1; off < 256; off <<= 1) {
    const int v = (t >= off) ? s[t - off] : 0;
    __syncthreads();
    s[t] += v;
    __syncthreads();
  }
  if (t < nb) boff[t] = (t == 0) ? 0 : s[t - 1];
}

__global__ __launch_bounds__(256) void scan_write_kernel(
    const int* __restrict__ deg, const int* __restrict__ boff,
    int* __restrict__ rowptr, int n, int E) {
  __shared__ int s[256];
  const int t = threadIdx.x;
  const int i = blockIdx.x * 256 + t;
  const int v = (i < n) ? deg[i] : 0;
  s[t] = v;
  __syncthreads();
  for (int off = 1; off < 256; off <<= 1) {
    const int u = (t >= off) ? s[t - off] : 0;
    __syncthreads();
    s[t] += u;
    __syncthreads();
  }
  if (i < n) {
    const int excl = boff[blockIdx.x] + s[t] - v;
    rowptr[i] = excl;
    if (i == n - 1) rowptr[n] = excl + v;  // == E
  }
}

__global__ __launch_bounds__(256) void fill_kernel(
    const int* __restrict__ src, const int* __restrict__ dst,
    const int* __restrict__ rowptr, int* __restrict__ cursor,
    int* __restrict__ csr_src, int E) {
  const int e = blockIdx.x * 256 + threadIdx.x;
  if (e < E) {
    const int d = dst[e];
    const int p = atomicAdd(&cursor[d], 1);
    csr_src[rowptr[d] + p] = src[e];
  }
}

// One wave per node; lean registers, deep MLP. hx[d] = x[d] + sum x[src].
__global__ __launch_bounds__(256, 8) void gather_kernel(
    const float* __restrict__ x, const int* __restrict__ rowptr,
    const int* __restrict__ csr_src, float* __restrict__ hx, int n) {
  const int lane = threadIdx.x & 63;
  const int wid = (blockIdx.x * 256 + threadIdx.x) >> 6;
  const int nwaves = (gridDim.x * 256) >> 6;
  for (int node = wid; node < n; node += nwaves) {
    const int nodeu = __builtin_amdgcn_readfirstlane(node);
    const int beg = rowptr[nodeu];
    const int end = rowptr[nodeu + 1];
    const int cnt = end - beg;
    float h0 = x[((unsigned)nodeu << 6) | lane];  // self
    float h1 = 0.f, h2 = 0.f, h3 = 0.f;
    int myi = 0;
    if (lane < cnt) myi = csr_src[beg + lane];
    const int c64 = cnt > 64 ? 64 : cnt;
    int i = 0;
    for (; i + 7 < c64; i += 8) {
      const unsigned r0 = (unsigned)__builtin_amdgcn_readlane(myi, i) << 6;
      const unsigned r1 = (unsigned)__builtin_amdgcn_readlane(myi, i + 1) << 6;
      const unsigned r2 = (unsigned)__builtin_amdgcn_readlane(myi, i + 2) << 6;
      const unsigned r3 = (unsigned)__builtin_amdgcn_readlane(myi, i + 3) << 6;
      const unsigned r4 = (unsigned)__builtin_amdgcn_readlane(myi, i + 4) << 6;
      const unsigned r5 = (unsigned)__builtin_amdgcn_readlane(myi, i + 5) << 6;
      const unsigned r6 = (unsigned)__builtin_amdgcn_readlane(myi, i + 6) << 6;
      const unsigned r7 = (unsigned)__builtin_amdgcn_readlane(myi, i + 7) << 6;
      const float v0 = x[r0 | lane];
      const float v1 = x[r1 | lane];
      const float v2 = x[r2 | lane];
      const float v3 = x[r3 | lane];
      const float v4 = x[r4 | lane];
      const float v5 = x[r5 | lane];
      const float v6 = x[r6 | lane];
      const float v7 = x[r7 | lane];
      h0 += v0 + v4;
      h1 += v1 + v5;
      h2 += v2 + v6;
      h3 += v3 + v7;
    }
    for (; i + 3 < c64; i += 4) {
      const unsigned r0 = (unsigned)__builtin_amdgcn_readlane(myi, i) << 6;
      const unsigned r1 = (unsigned)__builtin_amdgcn_readlane(myi, i + 1) << 6;
      const unsigned r2 = (unsigned)__builtin_amdgcn_readlane(myi, i + 2) << 6;
      const unsigned r3 = (unsigned)__builtin_amdgcn_readlane(myi, i + 3) << 6;
      h0 += x[r0 | lane];
      h1 += x[r1 | lane];
      h2 += x[r2 | lane];
      h3 += x[r3 | lane];
    }
    for (; i < c64; ++i) {
      const unsigned r = (unsigned)__builtin_amdgcn_readlane(myi, i) << 6;
      h0 += x[r | lane];
    }
    for (int j = beg + 64; j < end; ++j) {  // deg>64 tail: ~never
      const int s = csr_src[j];
      h0 += x[((unsigned)s << 6) | lane];
    }
    hx[((unsigned)nodeu << 6) | lane] = (h0 + h1) + (h2 + h3);
  }
}

// Wave per node-pair: register-resident weight columns, readlane broadcast,
// next pair's rows prefetched during the unrolled FMA block.
__global__ __launch_bounds__(256, 3) void gemm_kernel(
    const float* __restrict__ hx, const float* __restrict__ xin,
    const float* __restrict__ W1g, const float* __restrict__ Wu,
    const float* __restrict__ bu, const float* __restrict__ dvec,
    const int* __restrict__ deg, float* __restrict__ out, int npairs) {
  const int lane = threadIdx.x & 63;
  const int wid = (blockIdx.x * 256 + threadIdx.x) >> 6;
  const int nwaves = (gridDim.x * 256) >> 6;

  float w1[64], w2[64];
#pragma unroll
  for (int k = 0; k < 64; ++k) w1[k] = W1g[k * 64 + lane];
#pragma unroll
  for (int k = 0; k < 64; ++k) w2[k] = Wu[(64 + k) * 64 + lane];
  const float bl = bu[lane];
  const float dl = dvec[lane];

  int p = wid;
  if (p >= npairs) return;
  unsigned n0 = (unsigned)(2 * p), n1 = n0 + 1;
  float a0 = hx[(n0 << 6) | lane];
  float a1 = hx[(n1 << 6) | lane];
  float b0 = xin[(n0 << 6) | lane];
  float b1 = xin[(n1 << 6) | lane];
  while (true) {
    const int pn = p + nwaves;
    float na0 = 0.f, na1 = 0.f, nb0 = 0.f, nb1 = 0.f;
    if (pn < npairs) {  // prefetch next pair while we FMA
      const unsigned m0 = (unsigned)(2 * pn), m1 = m0 + 1;
      na0 = hx[(m0 << 6) | lane];
      na1 = hx[(m1 << 6) | lane];
      nb0 = xin[(m0 << 6) | lane];
      nb1 = xin[(m1 << 6) | lane];
    }
    const int n0u = __builtin_amdgcn_readfirstlane((int)n0);
    const float deg0 = (float)(deg[n0u] + 1);
    const float deg1 = (float)(deg[n0u + 1] + 1);
    float acc0 = fmaf(deg0, dl, bl);
    float acc1 = fmaf(deg1, dl, bl);
#pragma unroll
    for (int k = 0; k < 64; ++k) {
      const float hk0 = __uint_as_float(__builtin_amdgcn_readlane(__float_as_uint(a0), k));
      const float hk1 = __uint_as_float(__builtin_amdgcn_readlane(__float_as_uint(a1), k));
      const float xk0 = __uint_as_float(__builtin_amdgcn_readlane(__float_as_uint(b0), k));
      const float xk1 = __uint_as_float(__builtin_amdgcn_readlane(__float_as_uint(b1), k));
      acc0 = fmaf(hk0, w1[k], fmaf(xk0, w2[k], acc0));
      acc1 = fmaf(hk1, w1[k], fmaf(xk1, w2[k], acc1));
    }
    out[(n0 << 6) | lane] = acc0 > 0.f ? acc0 : 0.f;
    out[(n1 << 6) | lane] = acc1 > 0.f ? acc1 : 0.f;
    if (pn >= npairs) break;
    p = pn;
    n0 = (unsigned)(2 * p);
    n1 = n0 + 1;
    a0 = na0;
    a1 = na1;
    b0 = nb0;
    b1 = nb1;
  }
}

extern "C" void kernel_launch(void* const* d_in, const int* in_sizes, int n_in,
                              void* d_out, int out_size, void* d_ws, size_t ws_size,
                              hipStream_t stream) {
  const float* x = (const float*)d_in[0];
  const int* ei = (const int*)d_in[1];
  const int n = in_sizes[0] / DIM;   // 50000
  const int E = in_sizes[1] / 2;     // 800000
  const int* srcp = ei;
  const int* dstp = ei + E;
  const int nb = (n + 255) / 256;    // scan blocks (196)

  // Workspace layout:
  float* hx = (float*)d_ws;                    // n*64 floats
  float* y = hx + (size_t)n * DIM;             // n*64 floats (layer-1 output)
  int* deg = (int*)(y + (size_t)n * DIM);      // n      } contiguous for one
  int* cursor = deg + n;                       // n      } memset
  int* rowptr = cursor + n;                    // n+1
  int* csr_src = rowptr + n + 1;               // E
  float* W1 = (float*)(csr_src + E);           // 3*4096
  float* dv = W1 + 3 * 4096;                   // 3*64
  int* bsum = (int*)(dv + 3 * 64);             // 256
  int* boff = bsum + 256;                      // 256

  // One-time prep: fused weights + CSR build.
  fuse_weights_kernel<<<3, 256, 0, stream>>>(
      (const float*)d_in[2], (const float*)d_in[3], (const float*)d_in[4],
      (const float*)d_in[6], (const float*)d_in[7], (const float*)d_in[8],
      (const float*)d_in[10], (const float*)d_in[11], (const float*)d_in[12],
      W1, dv);
  hipMemsetAsync(deg, 0, 2 * (size_t)n * sizeof(int), stream);  // deg + cursor
  deg_kernel<<<(E + 255) / 256, 256, 0, stream>>>(dstp, deg, E);
  scan_sum_kernel<<<nb, 256, 0, stream>>>(deg, bsum, n);
  scan_block_kernel<<<1, 256, 0, stream>>>(bsum, boff, nb);
  scan_write_kernel<<<nb, 256, 0, stream>>>(deg, boff, rowptr, n, E);
  fill_kernel<<<(E + 255) / 256, 256, 0, stream>>>(srcp, dstp, rowptr, cursor, csr_src, E);

  // Layer chain: x -> d_out -> y -> d_out (d_out doubles as scratch)
  float* outs[3] = {(float*)d_out, y, (float*)d_out};
  const float* xin = x;
  const int npairs = n / 2;
  for (int l = 0; l < 3; ++l) {
    gather_kernel<<<2048, 256, 0, stream>>>(xin, rowptr, csr_src, hx, n);
    gemm_kernel<<<768, 256, 0, stream>>>(
        hx, xin, W1 + l * 4096, (const float*)d_in[4 + 4 * l],
        (const float*)d_in[5 + 4 * l], dv + l * 64, deg, outs[l], npairs);
    xin = outs[l];
  }
}

// Round 5
// 392.376 us; speedup vs baseline: 2.1967x; 2.1967x over previous
//
#include <hip/hip_runtime.h>

// MPNN, 3 layers, N=50000, E=800000, D=64, fp32.
//   hx[d] = x[d] + sum_{e: dst=d} x[src_e]            (CSR gather kernel)
//   out   = relu(hx@W1 + x@W2 + bu + (deg+1)*dvec)    (streaming GEMM kernel)
// W1 = Wm @ Wu_top, W2 = Wu_bot, dvec = bm @ Wu_top   (precomputed once)
// gemm_kernel MUST NOT have a min-waves launch-bound: the per-lane weight
// arrays (128 floats) need the ~230-reg/wave regime (2 waves/SIMD). A
// min-waves=3 bound caps regs at ~170 and spills the weights to scratch
// (round 4: FETCH 447 MB, 247 us vs ideal 26 MB).

#define DIM 64

__global__ __launch_bounds__(256) void fuse_weights_kernel(
    const float* __restrict__ Wm0, const float* __restrict__ bm0, const float* __restrict__ Wu0,
    const float* __restrict__ Wm1, const float* __restrict__ bm1, const float* __restrict__ Wu1,
    const float* __restrict__ Wm2, const float* __restrict__ bm2, const float* __restrict__ Wu2,
    float* __restrict__ W1, float* __restrict__ dv) {
  const int l = blockIdx.x;
  const float* Wm = l == 0 ? Wm0 : l == 1 ? Wm1 : Wm2;
  const float* bm = l == 0 ? bm0 : l == 1 ? bm1 : bm2;
  const float* Wu = l == 0 ? Wu0 : l == 1 ? Wu1 : Wu2;
  float* W1l = W1 + l * 4096;
  float* dvl = dv + l * 64;
  __shared__ float sWm[64 * 64];
  __shared__ float sWu[64 * 64];  // top half of Wu (rows 0..63)
  const int tid = threadIdx.x;
  for (int i = tid; i < 4096; i += 256) {
    sWm[i] = Wm[i];
    sWu[i] = Wu[i];
  }
  __syncthreads();
  for (int i = tid; i < 4096; i += 256) {
    const int r = i >> 6, c = i & 63;
    float acc = 0.f;
#pragma unroll
    for (int k = 0; k < 64; ++k) acc = fmaf(sWm[r * 64 + k], sWu[k * 64 + c], acc);
    W1l[i] = acc;
  }
  if (tid < 64) {
    float acc = 0.f;
#pragma unroll
    for (int k = 0; k < 64; ++k) acc = fmaf(bm[k], sWu[k * 64 + tid], acc);
    dvl[tid] = acc;
  }
}

__global__ __launch_bounds__(256) void deg_kernel(const int* __restrict__ dst,
                                                  int* __restrict__ deg, int E) {
  const int e = blockIdx.x * 256 + threadIdx.x;
  if (e < E) atomicAdd(&deg[dst[e]], 1);
}

// 3-phase multi-block exclusive scan of deg -> rowptr
__global__ __launch_bounds__(256) void scan_sum_kernel(const int* __restrict__ deg,
                                                       int* __restrict__ bsum, int n) {
  const int i = blockIdx.x * 256 + threadIdx.x;
  int v = (i < n) ? deg[i] : 0;
#pragma unroll
  for (int off = 1; off < 64; off <<= 1) v += __shfl_down(v, off, 64);
  __shared__ int ws[4];
  if ((threadIdx.x & 63) == 0) ws[threadIdx.x >> 6] = v;
  __syncthreads();
  if (threadIdx.x == 0) bsum[blockIdx.x] = ws[0] + ws[1] + ws[2] + ws[3];
}

__global__ __launch_bounds__(256) void scan_block_kernel(const int* __restrict__ bsum,
                                                         int* __restrict__ boff, int nb) {
  __shared__ int s[256];
  const int t = threadIdx.x;
  s[t] = (t < nb) ? bsum[t] : 0;
  __syncthreads();
  for (int off = 1; off < 256; off <<= 1) {
    const int v = (t >= off) ? s[t - off] : 0;
    __syncthreads();
    s[t] += v;
    __syncthreads();
  }
  if (t < nb) boff[t] = (t == 0) ? 0 : s[t - 1];
}

__global__ __launch_bounds__(256) void scan_write_kernel(
    const int* __restrict__ deg, const int* __restrict__ boff,
    int* __restrict__ rowptr, int n, int E) {
  __shared__ int s[256];
  const int t = threadIdx.x;
  const int i = blockIdx.x * 256 + t;
  const int v = (i < n) ? deg[i] : 0;
  s[t] = v;
  __syncthreads();
  for (int off = 1; off < 256; off <<= 1) {
    const int u = (t >= off) ? s[t - off] : 0;
    __syncthreads();
    s[t] += u;
    __syncthreads();
  }
  if (i < n) {
    const int excl = boff[blockIdx.x] + s[t] - v;
    rowptr[i] = excl;
    if (i == n - 1) rowptr[n] = excl + v;  // == E
  }
}

__global__ __launch_bounds__(256) void fill_kernel(
    const int* __restrict__ src, const int* __restrict__ dst,
    const int* __restrict__ rowptr, int* __restrict__ cursor,
    int* __restrict__ csr_src, int E) {
  const int e = blockIdx.x * 256 + threadIdx.x;
  if (e < E) {
    const int d = dst[e];
    const int p = atomicAdd(&cursor[d], 1);
    csr_src[rowptr[d] + p] = src[e];
  }
}

// One wave per node; lean registers, deep MLP. hx[d] = x[d] + sum x[src].
__global__ __launch_bounds__(256, 8) void gather_kernel(
    const float* __restrict__ x, const int* __restrict__ rowptr,
    const int* __restrict__ csr_src, float* __restrict__ hx, int n) {
  const int lane = threadIdx.x & 63;
  const int wid = (blockIdx.x * 256 + threadIdx.x) >> 6;
  const int nwaves = (gridDim.x * 256) >> 6;
  for (int node = wid; node < n; node += nwaves) {
    const int nodeu = __builtin_amdgcn_readfirstlane(node);
    const int beg = rowptr[nodeu];
    const int end = rowptr[nodeu + 1];
    const int cnt = end - beg;
    float h0 = x[((unsigned)nodeu << 6) | lane];  // self
    float h1 = 0.f, h2 = 0.f, h3 = 0.f;
    int myi = 0;
    if (lane < cnt) myi = csr_src[beg + lane];
    const int c64 = cnt > 64 ? 64 : cnt;
    int i = 0;
    for (; i + 7 < c64; i += 8) {
      const unsigned r0 = (unsigned)__builtin_amdgcn_readlane(myi, i) << 6;
      const unsigned r1 = (unsigned)__builtin_amdgcn_readlane(myi, i + 1) << 6;
      const unsigned r2 = (unsigned)__builtin_amdgcn_readlane(myi, i + 2) << 6;
      const unsigned r3 = (unsigned)__builtin_amdgcn_readlane(myi, i + 3) << 6;
      const unsigned r4 = (unsigned)__builtin_amdgcn_readlane(myi, i + 4) << 6;
      const unsigned r5 = (unsigned)__builtin_amdgcn_readlane(myi, i + 5) << 6;
      const unsigned r6 = (unsigned)__builtin_amdgcn_readlane(myi, i + 6) << 6;
      const unsigned r7 = (unsigned)__builtin_amdgcn_readlane(myi, i + 7) << 6;
      const float v0 = x[r0 | lane];
      const float v1 = x[r1 | lane];
      const float v2 = x[r2 | lane];
      const float v3 = x[r3 | lane];
      const float v4 = x[r4 | lane];
      const float v5 = x[r5 | lane];
      const float v6 = x[r6 | lane];
      const float v7 = x[r7 | lane];
      h0 += v0 + v4;
      h1 += v1 + v5;
      h2 += v2 + v6;
      h3 += v3 + v7;
    }
    for (; i + 3 < c64; i += 4) {
      const unsigned r0 = (unsigned)__builtin_amdgcn_readlane(myi, i) << 6;
      const unsigned r1 = (unsigned)__builtin_amdgcn_readlane(myi, i + 1) << 6;
      const unsigned r2 = (unsigned)__builtin_amdgcn_readlane(myi, i + 2) << 6;
      const unsigned r3 = (unsigned)__builtin_amdgcn_readlane(myi, i + 3) << 6;
      h0 += x[r0 | lane];
      h1 += x[r1 | lane];
      h2 += x[r2 | lane];
      h3 += x[r3 | lane];
    }
    for (; i < c64; ++i) {
      const unsigned r = (unsigned)__builtin_amdgcn_readlane(myi, i) << 6;
      h0 += x[r | lane];
    }
    for (int j = beg + 64; j < end; ++j) {  // deg>64 tail: ~never
      const int s = csr_src[j];
      h0 += x[((unsigned)s << 6) | lane];
    }
    hx[((unsigned)nodeu << 6) | lane] = (h0 + h1) + (h2 + h3);
  }
}

// Wave per node-pair: register-resident weight columns, readlane broadcast,
// next pair's rows prefetched during the unrolled FMA block.
// NO min-waves launch bound (see header comment).
__global__ __launch_bounds__(256) void gemm_kernel(
    const float* __restrict__ hx, const float* __restrict__ xin,
    const float* __restrict__ W1g, const float* __restrict__ Wu,
    const float* __restrict__ bu, const float* __restrict__ dvec,
    const int* __restrict__ deg, float* __restrict__ out, int npairs) {
  const int lane = threadIdx.x & 63;
  const int wid = (blockIdx.x * 256 + threadIdx.x) >> 6;
  const int nwaves = (gridDim.x * 256) >> 6;

  float w1[64], w2[64];
#pragma unroll
  for (int k = 0; k < 64; ++k) w1[k] = W1g[k * 64 + lane];
#pragma unroll
  for (int k = 0; k < 64; ++k) w2[k] = Wu[(64 + k) * 64 + lane];
  const float bl = bu[lane];
  const float dl = dvec[lane];

  int p = wid;
  if (p >= npairs) return;
  unsigned n0 = (unsigned)(2 * p), n1 = n0 + 1;
  float a0 = hx[(n0 << 6) | lane];
  float a1 = hx[(n1 << 6) | lane];
  float b0 = xin[(n0 << 6) | lane];
  float b1 = xin[(n1 << 6) | lane];
  while (true) {
    const int pn = p + nwaves;
    float na0 = 0.f, na1 = 0.f, nb0 = 0.f, nb1 = 0.f;
    if (pn < npairs) {  // prefetch next pair while we FMA
      const unsigned m0 = (unsigned)(2 * pn), m1 = m0 + 1;
      na0 = hx[(m0 << 6) | lane];
      na1 = hx[(m1 << 6) | lane];
      nb0 = xin[(m0 << 6) | lane];
      nb1 = xin[(m1 << 6) | lane];
    }
    const int n0u = __builtin_amdgcn_readfirstlane((int)n0);
    const float deg0 = (float)(deg[n0u] + 1);
    const float deg1 = (float)(deg[n0u + 1] + 1);
    float acc0 = fmaf(deg0, dl, bl);
    float acc1 = fmaf(deg1, dl, bl);
#pragma unroll
    for (int k = 0; k < 64; ++k) {
      const float hk0 = __uint_as_float(__builtin_amdgcn_readlane(__float_as_uint(a0), k));
      const float hk1 = __uint_as_float(__builtin_amdgcn_readlane(__float_as_uint(a1), k));
      const float xk0 = __uint_as_float(__builtin_amdgcn_readlane(__float_as_uint(b0), k));
      const float xk1 = __uint_as_float(__builtin_amdgcn_readlane(__float_as_uint(b1), k));
      acc0 = fmaf(hk0, w1[k], fmaf(xk0, w2[k], acc0));
      acc1 = fmaf(hk1, w1[k], fmaf(xk1, w2[k], acc1));
    }
    out[(n0 << 6) | lane] = acc0 > 0.f ? acc0 : 0.f;
    out[(n1 << 6) | lane] = acc1 > 0.f ? acc1 : 0.f;
    if (pn >= npairs) break;
    p = pn;
    n0 = (unsigned)(2 * p);
    n1 = n0 + 1;
    a0 = na0;
    a1 = na1;
    b0 = nb0;
    b1 = nb1;
  }
}

extern "C" void kernel_launch(void* const* d_in, const int* in_sizes, int n_in,
                              void* d_out, int out_size, void* d_ws, size_t ws_size,
                              hipStream_t stream) {
  const float* x = (const float*)d_in[0];
  const int* ei = (const int*)d_in[1];
  const int n = in_sizes[0] / DIM;   // 50000
  const int E = in_sizes[1] / 2;     // 800000
  const int* srcp = ei;
  const int* dstp = ei + E;
  const int nb = (n + 255) / 256;    // scan blocks (196)

  // Workspace layout:
  float* hx = (float*)d_ws;                    // n*64 floats
  float* y = hx + (size_t)n * DIM;             // n*64 floats (layer-1 output)
  int* deg = (int*)(y + (size_t)n * DIM);      // n      } contiguous for one
  int* cursor = deg + n;                       // n      } memset
  int* rowptr = cursor + n;                    // n+1
  int* csr_src = rowptr + n + 1;               // E
  float* W1 = (float*)(csr_src + E);           // 3*4096
  float* dv = W1 + 3 * 4096;                   // 3*64
  int* bsum = (int*)(dv + 3 * 64);             // 256
  int* boff = bsum + 256;                      // 256

  // One-time prep: fused weights + CSR build.
  fuse_weights_kernel<<<3, 256, 0, stream>>>(
      (const float*)d_in[2], (const float*)d_in[3], (const float*)d_in[4],
      (const float*)d_in[6], (const float*)d_in[7], (const float*)d_in[8],
      (const float*)d_in[10], (const float*)d_in[11], (const float*)d_in[12],
      W1, dv);
  hipMemsetAsync(deg, 0, 2 * (size_t)n * sizeof(int), stream);  // deg + cursor
  deg_kernel<<<(E + 255) / 256, 256, 0, stream>>>(dstp, deg, E);
  scan_sum_kernel<<<nb, 256, 0, stream>>>(deg, bsum, n);
  scan_block_kernel<<<1, 256, 0, stream>>>(bsum, boff, nb);
  scan_write_kernel<<<nb, 256, 0, stream>>>(deg, boff, rowptr, n, E);
  fill_kernel<<<(E + 255) / 256, 256, 0, stream>>>(srcp, dstp, rowptr, cursor, csr_src, E);

  // Layer chain: x -> d_out -> y -> d_out (d_out doubles as scratch)
  float* outs[3] = {(float*)d_out, y, (float*)d_out};
  const float* xin = x;
  const int npairs = n / 2;
  for (int l = 0; l < 3; ++l) {
    gather_kernel<<<2048, 256, 0, stream>>>(xin, rowptr, csr_src, hx, n);
    gemm_kernel<<<1024, 256, 0, stream>>>(
        hx, xin, W1 + l * 4096, (const float*)d_in[4 + 4 * l],
        (const float*)d_in[5 + 4 * l], dv + l * 64, deg, outs[l], npairs);
    xin = outs[l];
  }
}

// Round 6
// 216.853 us; speedup vs baseline: 3.9748x; 1.8094x over previous
//
#include <hip/hip_runtime.h>
#include <hip/hip_fp16.h>

// MPNN, 3 layers, N=50000, E=800000, D=64.
//   hx[d] = x[d] + sum_{e: dst=d} x[src_e]            (CSR gather, fp16 data, fp32 accum)
//   out   = relu([hx | x] @ Wt^T + bu + (deg+1)*dvec) (fp16 MFMA, fp32 accum)
// Wt[n][k] = k<64 ? (Wm@Wu_top)[k][n] : Wu_bot[k-64][n]   (fp16, precomputed)
// dvec = bm @ Wu_top.
//
// Learned constraints:
//  - NO min-waves launch bound on register-heavy kernels (r4: spilled to scratch).
//  - MFMA A/B fragment k-layout need not be known: A and B share the same
//    (group g=lane>>4, elem j) -> k map, so feeding both with f(g,j)=8g+j
//    (contiguous 16B loads) computes exact A*B. C/D: col=lane&15, row=4*(lane>>4)+reg.
//  - LDS A-tile: rows stride 128B = all-same-bank; XOR-swizzle chunk^=(row&7).

#define DIM 64

typedef _Float16 f16x8 __attribute__((ext_vector_type(8)));
typedef float f32x4 __attribute__((ext_vector_type(4)));

static __device__ __forceinline__ float lo16(unsigned u) {
  return __half2float(__ushort_as_half((unsigned short)(u & 0xFFFFu)));
}
static __device__ __forceinline__ float hi16(unsigned u) {
  return __half2float(__ushort_as_half((unsigned short)(u >> 16)));
}
static __device__ __forceinline__ unsigned pack16(float a, float b) {
  return (unsigned)__half_as_ushort(__float2half(a)) |
         ((unsigned)__half_as_ushort(__float2half(b)) << 16);
}

__global__ __launch_bounds__(256) void fuse_weights_kernel(
    const float* __restrict__ Wm0, const float* __restrict__ bm0, const float* __restrict__ Wu0,
    const float* __restrict__ Wm1, const float* __restrict__ bm1, const float* __restrict__ Wu1,
    const float* __restrict__ Wm2, const float* __restrict__ bm2, const float* __restrict__ Wu2,
    unsigned short* __restrict__ Wtb, float* __restrict__ dv) {
  const int l = blockIdx.x;
  const float* Wm = l == 0 ? Wm0 : l == 1 ? Wm1 : Wm2;
  const float* bm = l == 0 ? bm0 : l == 1 ? bm1 : bm2;
  const float* Wu = l == 0 ? Wu0 : l == 1 ? Wu1 : Wu2;
  __shared__ float sWm[4096];
  __shared__ float sWu[4096];   // top half of Wu (rows 0..63)
  __shared__ float sW1[4096];   // Wm @ Wu_top
  const int tid = threadIdx.x;
  for (int i = tid; i < 4096; i += 256) {
    sWm[i] = Wm[i];
    sWu[i] = Wu[i];
  }
  __syncthreads();
  for (int i = tid; i < 4096; i += 256) {
    const int r = i >> 6, c = i & 63;
    float acc = 0.f;
#pragma unroll
    for (int k = 0; k < 64; ++k) acc = fmaf(sWm[r * 64 + k], sWu[k * 64 + c], acc);
    sW1[i] = acc;
  }
  __syncthreads();
  // Wt[n][k], 64x128 fp16 row-major: k<64 -> W1[k][n]; k>=64 -> Wu[k][n] (row k of Wu is Wu_bot row k-64)
  unsigned short* Wl = Wtb + (size_t)l * 8192;
  for (int i = tid; i < 8192; i += 256) {
    const int ncol = i >> 7, k = i & 127;
    const float v = (k < 64) ? sW1[k * 64 + ncol] : Wu[k * 64 + ncol];
    Wl[i] = __half_as_ushort(__float2half(v));
  }
  if (tid < 64) {
    float acc = 0.f;
#pragma unroll
    for (int k = 0; k < 64; ++k) acc = fmaf(bm[k], sWu[k * 64 + tid], acc);
    dv[l * 64 + tid] = acc;
  }
}

__global__ __launch_bounds__(256) void convert_kernel(const float* __restrict__ x,
                                                      unsigned* __restrict__ xb2,
                                                      int nquads) {
  const int i = blockIdx.x * 256 + threadIdx.x;
  if (i < nquads) {
    const float4 v = ((const float4*)x)[i];
    xb2[2 * i] = pack16(v.x, v.y);
    xb2[2 * i + 1] = pack16(v.z, v.w);
  }
}

__global__ __launch_bounds__(256) void deg_kernel(const int* __restrict__ dst,
                                                  int* __restrict__ deg, int E) {
  const int e = blockIdx.x * 256 + threadIdx.x;
  if (e < E) atomicAdd(&deg[dst[e]], 1);
}

// 3-phase multi-block exclusive scan of deg -> rowptr
__global__ __launch_bounds__(256) void scan_sum_kernel(const int* __restrict__ deg,
                                                       int* __restrict__ bsum, int n) {
  const int i = blockIdx.x * 256 + threadIdx.x;
  int v = (i < n) ? deg[i] : 0;
#pragma unroll
  for (int off = 1; off < 64; off <<= 1) v += __shfl_down(v, off, 64);
  __shared__ int ws[4];
  if ((threadIdx.x & 63) == 0) ws[threadIdx.x >> 6] = v;
  __syncthreads();
  if (threadIdx.x == 0) bsum[blockIdx.x] = ws[0] + ws[1] + ws[2] + ws[3];
}

__global__ __launch_bounds__(256) void scan_block_kernel(const int* __restrict__ bsum,
                                                         int* __restrict__ boff, int nb) {
  __shared__ int s[256];
  const int t = threadIdx.x;
  s[t] = (t < nb) ? bsum[t] : 0;
  __syncthreads();
  for (int off = 1; off < 256; off <<= 1) {
    const int v = (t >= off) ? s[t - off] : 0;
    __syncthreads();
    s[t] += v;
    __syncthreads();
  }
  if (t < nb) boff[t] = (t == 0) ? 0 : s[t - 1];
}

__global__ __launch_bounds__(256) void scan_write_kernel(
    const int* __restrict__ deg, const int* __restrict__ boff,
    int* __restrict__ rowptr, int n, int E) {
  __shared__ int s[256];
  const int t = threadIdx.x;
  const int i = blockIdx.x * 256 + t;
  const int v = (i < n) ? deg[i] : 0;
  s[t] = v;
  __syncthreads();
  for (int off = 1; off < 256; off <<= 1) {
    const int u = (t >= off) ? s[t - off] : 0;
    __syncthreads();
    s[t] += u;
    __syncthreads();
  }
  if (i < n) {
    const int excl = boff[blockIdx.x] + s[t] - v;
    rowptr[i] = excl;
    if (i == n - 1) rowptr[n] = excl + v;
  }
}

__global__ __launch_bounds__(256) void fill_kernel(
    const int* __restrict__ src, const int* __restrict__ dst,
    const int* __restrict__ rowptr, int* __restrict__ cursor,
    int* __restrict__ csr_src, int E) {
  const int e = blockIdx.x * 256 + threadIdx.x;
  if (e < E) {
    const int d = dst[e];
    const int p = atomicAdd(&cursor[d], 1);
    csr_src[rowptr[d] + p] = src[e];
  }
}

// One wave per node, fp16 rows. Each load instr fetches TWO neighbor rows:
// half-wave h (lane>>5) picks the neighbor, 32 lanes x uint = one 128B row.
__global__ __launch_bounds__(256, 8) void gather_kernel(
    const unsigned* __restrict__ xu,   // fp16 x, 2 cols per uint, 32 uints/row
    const int* __restrict__ rowptr, const int* __restrict__ csr_src,
    unsigned* __restrict__ hxu, int n) {
  const int lane = threadIdx.x & 63;
  const int j = lane & 31;
  const int h = lane >> 5;
  const int wid = (blockIdx.x * 256 + threadIdx.x) >> 6;
  const int nwaves = (gridDim.x * 256) >> 6;
  for (int node = wid; node < n; node += nwaves) {
    const int nodeu = __builtin_amdgcn_readfirstlane(node);
    const int beg = rowptr[nodeu];
    const int end = rowptr[nodeu + 1];
    const int cnt = end - beg;
    int myi = 0;
    if (lane < cnt) myi = csr_src[beg + lane];
    const int c64 = cnt > 64 ? 64 : cnt;
    float a0 = 0.f, a1 = 0.f, b0 = 0.f, b1 = 0.f;
    int i = 0;
    for (; i + 7 < c64; i += 8) {  // 4 pair-steps, 4 outstanding loads
      const int sA = __builtin_amdgcn_readlane(myi, i);
      const int sB = __builtin_amdgcn_readlane(myi, i + 1);
      const int sC = __builtin_amdgcn_readlane(myi, i + 2);
      const int sD = __builtin_amdgcn_readlane(myi, i + 3);
      const int sE = __builtin_amdgcn_readlane(myi, i + 4);
      const int sF = __builtin_amdgcn_readlane(myi, i + 5);
      const int sG = __builtin_amdgcn_readlane(myi, i + 6);
      const int sH = __builtin_amdgcn_readlane(myi, i + 7);
      const unsigned u0 = xu[(unsigned)(h ? sB : sA) * 32 + j];
      const unsigned u1 = xu[(unsigned)(h ? sD : sC) * 32 + j];
      const unsigned u2 = xu[(unsigned)(h ? sF : sE) * 32 + j];
      const unsigned u3 = xu[(unsigned)(h ? sH : sG) * 32 + j];
      a0 += lo16(u0); a1 += hi16(u0);
      b0 += lo16(u1); b1 += hi16(u1);
      a0 += lo16(u2); a1 += hi16(u2);
      b0 += lo16(u3); b1 += hi16(u3);
    }
    for (; i + 1 < c64; i += 2) {
      const int sA = __builtin_amdgcn_readlane(myi, i);
      const int sB = __builtin_amdgcn_readlane(myi, i + 1);
      const unsigned u = xu[(unsigned)(h ? sB : sA) * 32 + j];
      a0 += lo16(u); a1 += hi16(u);
    }
    if (i < c64 && h == 0) {  // odd tail: low half only
      const int sA = __builtin_amdgcn_readlane(myi, i);
      const unsigned u = xu[(unsigned)sA * 32 + j];
      a0 += lo16(u); a1 += hi16(u);
    }
    for (int t = beg + 64; t < end; ++t) {  // deg>64: ~never
      if (h == 0) {
        const unsigned u = xu[(unsigned)csr_src[t] * 32 + j];
        a0 += lo16(u); a1 += hi16(u);
      }
    }
    a0 += b0; a1 += b1;
    a0 += __shfl_xor(a0, 32, 64);
    a1 += __shfl_xor(a1, 32, 64);
    if (h == 0) {
      const unsigned us = xu[(unsigned)nodeu * 32 + j];  // self
      hxu[(unsigned)nodeu * 32 + j] = pack16(a0 + lo16(us), a1 + hi16(us));
    }
  }
}

// 64 rows per block (4 waves x 16). A = [hx | x] (K=128) staged in swizzled
// LDS; B = Wt[n][k] fragments loaded as contiguous 16B; 16 MFMAs per wave.
template <int OUT_F32>
__global__ __launch_bounds__(256) void gemm_kernel(
    const unsigned short* __restrict__ hxb, const unsigned short* __restrict__ xb,
    const unsigned short* __restrict__ Wtb, const float* __restrict__ bu,
    const float* __restrict__ dvec, const int* __restrict__ deg,
    void* __restrict__ outp, int n) {
  __shared__ unsigned short lhx[64 * 64];
  __shared__ unsigned short lx[64 * 64];
  const int tid = threadIdx.x;
  const int base = blockIdx.x * 64;
  {  // stage 64 rows of hx and x, XOR-swizzled 16B chunks
    const uint4* ghx = (const uint4*)hxb;
    const uint4* gx = (const uint4*)xb;
    uint4* shx = (uint4*)lhx;
    uint4* sx = (uint4*)lx;
    for (int t = tid; t < 512; t += 256) {
      const int row = t >> 3, c = t & 7;
      const int grow = base + row;
      uint4 vh = make_uint4(0, 0, 0, 0), vx = make_uint4(0, 0, 0, 0);
      if (grow < n) {
        vh = ghx[(size_t)grow * 8 + c];
        vx = gx[(size_t)grow * 8 + c];
      }
      const int cs = c ^ (row & 7);
      shx[row * 8 + cs] = vh;
      sx[row * 8 + cs] = vx;
    }
  }
  const int lane = tid & 63;
  const int w = tid >> 6;
  const int l15 = lane & 15, lg = lane >> 4;
  // B fragments: b[ct][kq], elem j = Wt[ct*16+l15][kq*32 + 8*lg + j]
  f16x8 bfr[16];
#pragma unroll
  for (int ct = 0; ct < 4; ++ct)
#pragma unroll
    for (int kq = 0; kq < 4; ++kq)
      bfr[ct * 4 + kq] = *(const f16x8*)((const char*)Wtb + (ct * 16 + l15) * 256 + kq * 64 + lg * 16);
  __syncthreads();
  f32x4 acc[4] = {0, 0, 0, 0};
  const int rt = w * 16 + l15;  // A row within tile
#pragma unroll
  for (int kq = 0; kq < 4; ++kq) {
    const unsigned short* mat = (kq < 2) ? lhx : lx;
    const int chunk = lg + 4 * (kq & 1);
    const int cs = chunk ^ (rt & 7);
    const f16x8 af = *(const f16x8*)((const char*)mat + rt * 128 + cs * 16);
#pragma unroll
    for (int ct = 0; ct < 4; ++ct)
      acc[ct] = __builtin_amdgcn_mfma_f32_16x16x32_f16(af, bfr[ct * 4 + kq], acc[ct], 0, 0, 0);
  }
  // epilogue: C/D row = 4*lg + r, col = ct*16 + l15
#pragma unroll
  for (int r = 0; r < 4; ++r) {
    const int row = base + w * 16 + lg * 4 + r;
    if (row < n) {
      const float dg = (float)(deg[row] + 1);
#pragma unroll
      for (int ct = 0; ct < 4; ++ct) {
        const int col = ct * 16 + l15;
        float v = acc[ct][r] + bu[col] + dg * dvec[col];
        v = v > 0.f ? v : 0.f;
        if (OUT_F32)
          ((float*)outp)[(size_t)row * 64 + col] = v;
        else
          ((unsigned short*)outp)[(size_t)row * 64 + col] = __half_as_ushort(__float2half(v));
      }
    }
  }
}

extern "C" void kernel_launch(void* const* d_in, const int* in_sizes, int n_in,
                              void* d_out, int out_size, void* d_ws, size_t ws_size,
                              hipStream_t stream) {
  const float* x = (const float*)d_in[0];
  const int* ei = (const int*)d_in[1];
  const int n = in_sizes[0] / DIM;   // 50000
  const int E = in_sizes[1] / 2;     // 800000
  const int* srcp = ei;
  const int* dstp = ei + E;
  const int nb = (n + 255) / 256;

  // Workspace layout (16B-alignment: fp16 buffers first, all sizes 16B-multiples)
  unsigned short* xb = (unsigned short*)d_ws;        // n*64 fp16
  unsigned short* hxb = xb + (size_t)n * DIM;        // n*64 fp16
  unsigned short* yb = hxb + (size_t)n * DIM;        // n*64 fp16
  unsigned short* Wtb = yb + (size_t)n * DIM;        // 3*8192 fp16 (16KB each)
  float* dv = (float*)(Wtb + 3 * 8192);              // 3*64
  int* deg = (int*)(dv + 3 * 64);                    // n   } contiguous for one
  int* cursor = deg + n;                             // n   } memset
  int* rowptr = cursor + n;                          // n+1
  int* csr_src = rowptr + n + 1;                     // E
  int* bsum = csr_src + E;                           // 256
  int* boff = bsum + 256;                            // 256

  // One-time prep: fused fp16 weights, fp16 x, CSR build.
  fuse_weights_kernel<<<3, 256, 0, stream>>>(
      (const float*)d_in[2], (const float*)d_in[3], (const float*)d_in[4],
      (const float*)d_in[6], (const float*)d_in[7], (const float*)d_in[8],
      (const float*)d_in[10], (const float*)d_in[11], (const float*)d_in[12],
      Wtb, dv);
  convert_kernel<<<(n * DIM / 4 + 255) / 256, 256, 0, stream>>>(x, (unsigned*)xb, n * DIM / 4);
  hipMemsetAsync(deg, 0, 2 * (size_t)n * sizeof(int), stream);
  deg_kernel<<<(E + 255) / 256, 256, 0, stream>>>(dstp, deg, E);
  scan_sum_kernel<<<nb, 256, 0, stream>>>(deg, bsum, n);
  scan_block_kernel<<<1, 256, 0, stream>>>(bsum, boff, nb);
  scan_write_kernel<<<nb, 256, 0, stream>>>(deg, boff, rowptr, n, E);
  fill_kernel<<<(E + 255) / 256, 256, 0, stream>>>(srcp, dstp, rowptr, cursor, csr_src, E);

  // Layer chain (fp16): xb -> yb -> xb -> d_out(fp32)
  const int gblocks = (n + 63) / 64;
  // layer 0
  gather_kernel<<<2048, 256, 0, stream>>>((const unsigned*)xb, rowptr, csr_src, (unsigned*)hxb, n);
  gemm_kernel<0><<<gblocks, 256, 0, stream>>>(hxb, xb, Wtb, (const float*)d_in[5], dv, deg, yb, n);
  // layer 1
  gather_kernel<<<2048, 256, 0, stream>>>((const unsigned*)yb, rowptr, csr_src, (unsigned*)hxb, n);
  gemm_kernel<0><<<gblocks, 256, 0, stream>>>(hxb, yb, Wtb + 8192, (const float*)d_in[9], dv + 64, deg, xb, n);
  // layer 2
  gather_kernel<<<2048, 256, 0, stream>>>((const unsigned*)xb, rowptr, csr_src, (unsigned*)hxb, n);
  gemm_kernel<1><<<gblocks, 256, 0, stream>>>(hxb, xb, Wtb + 16384, (const float*)d_in[13], dv + 128, deg, d_out, n);
}

// Round 7
// 202.897 us; speedup vs baseline: 4.2482x; 1.0688x over previous
//
#include <hip/hip_runtime.h>
#include <hip/hip_fp16.h>

// MPNN, 3 layers, N=50000, E=800000, D=64.
//   hx[d] = x[d] + sum_{e: dst=d} x[src_e]            (CSR gather, fp16 data, fp32 accum)
//   out   = relu([hx | x] @ Wt^T + bu + (deg+1)*dvec) (fp16 MFMA, fp32 accum)
// Wt[n][k] = k<64 ? (Wm@Wu_top)[k][n] : Wu_bot[k-64][n]   (fp16, precomputed)
//
// Learned constraints:
//  - NO min-waves launch bound on register-heavy kernels (r4: spilled to scratch).
//  - MFMA A/B share the (g=lane>>4, j) -> k map: feeding both with f(g,j)=8g+j
//    (contiguous 16B loads) computes exact A*B. C/D: col=lane&15, row=4*(lane>>4)+reg.
//  - LDS A-tile rows stride 128B = same-bank; XOR-swizzle chunk^=(row&7).
//  - fill is bound by scattered-store partial-line traffic (r6: 56MB WRITE @1TB/s
//    for a 3.2MB array) -> csr entries are ushort (N<65536), cursor pre-init to
//    rowptr kills the per-edge rowptr load.

#define DIM 64

typedef _Float16 f16x8 __attribute__((ext_vector_type(8)));
typedef float f32x4 __attribute__((ext_vector_type(4)));

static __device__ __forceinline__ float lo16(unsigned u) {
  return __half2float(__ushort_as_half((unsigned short)(u & 0xFFFFu)));
}
static __device__ __forceinline__ float hi16(unsigned u) {
  return __half2float(__ushort_as_half((unsigned short)(u >> 16)));
}
static __device__ __forceinline__ unsigned pack16(float a, float b) {
  return (unsigned)__half_as_ushort(__float2half(a)) |
         ((unsigned)__half_as_ushort(__float2half(b)) << 16);
}

__global__ __launch_bounds__(256) void fuse_weights_kernel(
    const float* __restrict__ Wm0, const float* __restrict__ bm0, const float* __restrict__ Wu0,
    const float* __restrict__ Wm1, const float* __restrict__ bm1, const float* __restrict__ Wu1,
    const float* __restrict__ Wm2, const float* __restrict__ bm2, const float* __restrict__ Wu2,
    unsigned short* __restrict__ Wtb, float* __restrict__ dv) {
  const int l = blockIdx.x;
  const float* Wm = l == 0 ? Wm0 : l == 1 ? Wm1 : Wm2;
  const float* bm = l == 0 ? bm0 : l == 1 ? bm1 : bm2;
  const float* Wu = l == 0 ? Wu0 : l == 1 ? Wu1 : Wu2;
  __shared__ float sWm[4096];
  __shared__ float sWu[4096];   // top half of Wu (rows 0..63)
  __shared__ float sW1[4096];   // Wm @ Wu_top
  const int tid = threadIdx.x;
  for (int i = tid; i < 4096; i += 256) {
    sWm[i] = Wm[i];
    sWu[i] = Wu[i];
  }
  __syncthreads();
  for (int i = tid; i < 4096; i += 256) {
    const int r = i >> 6, c = i & 63;
    float acc = 0.f;
#pragma unroll
    for (int k = 0; k < 64; ++k) acc = fmaf(sWm[r * 64 + k], sWu[k * 64 + c], acc);
    sW1[i] = acc;
  }
  __syncthreads();
  unsigned short* Wl = Wtb + (size_t)l * 8192;
  for (int i = tid; i < 8192; i += 256) {
    const int ncol = i >> 7, k = i & 127;
    const float v = (k < 64) ? sW1[k * 64 + ncol] : Wu[k * 64 + ncol];
    Wl[i] = __half_as_ushort(__float2half(v));
  }
  if (tid < 64) {
    float acc = 0.f;
#pragma unroll
    for (int k = 0; k < 64; ++k) acc = fmaf(bm[k], sWu[k * 64 + tid], acc);
    dv[l * 64 + tid] = acc;
  }
}

// Merged: fp32->fp16 convert of x (quad i) + degree count (edge i). Both 800k.
__global__ __launch_bounds__(256) void prep_kernel(
    const float* __restrict__ x, unsigned* __restrict__ xb2, int nquads,
    const int* __restrict__ dst, int* __restrict__ deg, int E) {
  const int i = blockIdx.x * 256 + threadIdx.x;
  if (i < nquads) {
    const float4 v = ((const float4*)x)[i];
    xb2[2 * i] = pack16(v.x, v.y);
    xb2[2 * i + 1] = pack16(v.z, v.w);
  }
  if (i < E) atomicAdd(&deg[dst[i]], 1);
}

// 3-phase multi-block exclusive scan of deg -> rowptr (and cursor = rowptr copy)
__global__ __launch_bounds__(256) void scan_sum_kernel(const int* __restrict__ deg,
                                                       int* __restrict__ bsum, int n) {
  const int i = blockIdx.x * 256 + threadIdx.x;
  int v = (i < n) ? deg[i] : 0;
#pragma unroll
  for (int off = 1; off < 64; off <<= 1) v += __shfl_down(v, off, 64);
  __shared__ int ws[4];
  if ((threadIdx.x & 63) == 0) ws[threadIdx.x >> 6] = v;
  __syncthreads();
  if (threadIdx.x == 0) bsum[blockIdx.x] = ws[0] + ws[1] + ws[2] + ws[3];
}

__global__ __launch_bounds__(256) void scan_block_kernel(const int* __restrict__ bsum,
                                                         int* __restrict__ boff, int nb) {
  __shared__ int s[256];
  const int t = threadIdx.x;
  s[t] = (t < nb) ? bsum[t] : 0;
  __syncthreads();
  for (int off = 1; off < 256; off <<= 1) {
    const int v = (t >= off) ? s[t - off] : 0;
    __syncthreads();
    s[t] += v;
    __syncthreads();
  }
  if (t < nb) boff[t] = (t == 0) ? 0 : s[t - 1];
}

__global__ __launch_bounds__(256) void scan_write_kernel(
    const int* __restrict__ deg, const int* __restrict__ boff,
    int* __restrict__ rowptr, int* __restrict__ cursor, int n) {
  __shared__ int s[256];
  const int t = threadIdx.x;
  const int i = blockIdx.x * 256 + t;
  const int v = (i < n) ? deg[i] : 0;
  s[t] = v;
  __syncthreads();
  for (int off = 1; off < 256; off <<= 1) {
    const int u = (t >= off) ? s[t - off] : 0;
    __syncthreads();
    s[t] += u;
    __syncthreads();
  }
  if (i < n) {
    const int excl = boff[blockIdx.x] + s[t] - v;
    rowptr[i] = excl;
    cursor[i] = excl;
    if (i == n - 1) rowptr[n] = excl + v;
  }
}

// 2 edges per thread; cursor pre-initialized to rowptr -> absolute slot directly.
__global__ __launch_bounds__(256) void fill_kernel(
    const int* __restrict__ src, const int* __restrict__ dst,
    int* __restrict__ cursor, unsigned short* __restrict__ csr16, int Epairs) {
  const int t = blockIdx.x * 256 + threadIdx.x;
  if (t < Epairs) {
    const int2 d2 = ((const int2*)dst)[t];
    const int2 s2 = ((const int2*)src)[t];
    const int p0 = atomicAdd(&cursor[d2.x], 1);
    csr16[p0] = (unsigned short)s2.x;
    const int p1 = atomicAdd(&cursor[d2.y], 1);
    csr16[p1] = (unsigned short)s2.y;
  }
}

// One wave per node, fp16 rows. Each load instr fetches TWO neighbor rows:
// half-wave h (lane>>5) picks the neighbor, 32 lanes x uint = one 128B row.
__global__ __launch_bounds__(256, 8) void gather_kernel(
    const unsigned* __restrict__ xu,   // fp16 x, 2 cols per uint, 32 uints/row
    const int* __restrict__ rowptr, const unsigned short* __restrict__ csr16,
    unsigned* __restrict__ hxu, int n) {
  const int lane = threadIdx.x & 63;
  const int j = lane & 31;
  const int h = lane >> 5;
  const int wid = (blockIdx.x * 256 + threadIdx.x) >> 6;
  const int nwaves = (gridDim.x * 256) >> 6;
  for (int node = wid; node < n; node += nwaves) {
    const int nodeu = __builtin_amdgcn_readfirstlane(node);
    const int beg = rowptr[nodeu];
    const int end = rowptr[nodeu + 1];
    const int cnt = end - beg;
    int myi = 0;
    if (lane < cnt) myi = (int)csr16[beg + lane];
    const int c64 = cnt > 64 ? 64 : cnt;
    float a0 = 0.f, a1 = 0.f, b0 = 0.f, b1 = 0.f;
    int i = 0;
    for (; i + 7 < c64; i += 8) {  // 4 pair-steps, 4 outstanding loads
      const int sA = __builtin_amdgcn_readlane(myi, i);
      const int sB = __builtin_amdgcn_readlane(myi, i + 1);
      const int sC = __builtin_amdgcn_readlane(myi, i + 2);
      const int sD = __builtin_amdgcn_readlane(myi, i + 3);
      const int sE = __builtin_amdgcn_readlane(myi, i + 4);
      const int sF = __builtin_amdgcn_readlane(myi, i + 5);
      const int sG = __builtin_amdgcn_readlane(myi, i + 6);
      const int sH = __builtin_amdgcn_readlane(myi, i + 7);
      const unsigned u0 = xu[(unsigned)(h ? sB : sA) * 32 + j];
      const unsigned u1 = xu[(unsigned)(h ? sD : sC) * 32 + j];
      const unsigned u2 = xu[(unsigned)(h ? sF : sE) * 32 + j];
      const unsigned u3 = xu[(unsigned)(h ? sH : sG) * 32 + j];
      a0 += lo16(u0); a1 += hi16(u0);
      b0 += lo16(u1); b1 += hi16(u1);
      a0 += lo16(u2); a1 += hi16(u2);
      b0 += lo16(u3); b1 += hi16(u3);
    }
    for (; i + 1 < c64; i += 2) {
      const int sA = __builtin_amdgcn_readlane(myi, i);
      const int sB = __builtin_amdgcn_readlane(myi, i + 1);
      const unsigned u = xu[(unsigned)(h ? sB : sA) * 32 + j];
      a0 += lo16(u); a1 += hi16(u);
    }
    if (i < c64 && h == 0) {  // odd tail: low half only
      const int sA = __builtin_amdgcn_readlane(myi, i);
      const unsigned u = xu[(unsigned)sA * 32 + j];
      a0 += lo16(u); a1 += hi16(u);
    }
    for (int t = beg + 64; t < end; ++t) {  // deg>64: ~never
      if (h == 0) {
        const unsigned u = xu[(unsigned)csr16[t] * 32 + j];
        a0 += lo16(u); a1 += hi16(u);
      }
    }
    a0 += b0; a1 += b1;
    a0 += __shfl_xor(a0, 32, 64);
    a1 += __shfl_xor(a1, 32, 64);
    if (h == 0) {
      const unsigned us = xu[(unsigned)nodeu * 32 + j];  // self
      hxu[(unsigned)nodeu * 32 + j] = pack16(a0 + lo16(us), a1 + hi16(us));
    }
  }
}

// 64 rows per block (4 waves x 16). A = [hx | x] (K=128) staged in swizzled
// LDS; B = Wt[n][k] fragments loaded as contiguous 16B; 16 MFMAs per wave.
template <int OUT_F32>
__global__ __launch_bounds__(256) void gemm_kernel(
    const unsigned short* __restrict__ hxb, const unsigned short* __restrict__ xb,
    const unsigned short* __restrict__ Wtb, const float* __restrict__ bu,
    const float* __restrict__ dvec, const int* __restrict__ deg,
    void* __restrict__ outp, int n) {
  __shared__ unsigned short lhx[64 * 64];
  __shared__ unsigned short lx[64 * 64];
  const int tid = threadIdx.x;
  const int base = blockIdx.x * 64;
  {
    const uint4* ghx = (const uint4*)hxb;
    const uint4* gx = (const uint4*)xb;
    uint4* shx = (uint4*)lhx;
    uint4* sx = (uint4*)lx;
    for (int t = tid; t < 512; t += 256) {
      const int row = t >> 3, c = t & 7;
      const int grow = base + row;
      uint4 vh = make_uint4(0, 0, 0, 0), vx = make_uint4(0, 0, 0, 0);
      if (grow < n) {
        vh = ghx[(size_t)grow * 8 + c];
        vx = gx[(size_t)grow * 8 + c];
      }
      const int cs = c ^ (row & 7);
      shx[row * 8 + cs] = vh;
      sx[row * 8 + cs] = vx;
    }
  }
  const int lane = tid & 63;
  const int w = tid >> 6;
  const int l15 = lane & 15, lg = lane >> 4;
  f16x8 bfr[16];
#pragma unroll
  for (int ct = 0; ct < 4; ++ct)
#pragma unroll
    for (int kq = 0; kq < 4; ++kq)
      bfr[ct * 4 + kq] = *(const f16x8*)((const char*)Wtb + (ct * 16 + l15) * 256 + kq * 64 + lg * 16);
  __syncthreads();
  f32x4 acc[4] = {0, 0, 0, 0};
  const int rt = w * 16 + l15;
#pragma unroll
  for (int kq = 0; kq < 4; ++kq) {
    const unsigned short* mat = (kq < 2) ? lhx : lx;
    const int chunk = lg + 4 * (kq & 1);
    const int cs = chunk ^ (rt & 7);
    const f16x8 af = *(const f16x8*)((const char*)mat + rt * 128 + cs * 16);
#pragma unroll
    for (int ct = 0; ct < 4; ++ct)
      acc[ct] = __builtin_amdgcn_mfma_f32_16x16x32_f16(af, bfr[ct * 4 + kq], acc[ct], 0, 0, 0);
  }
#pragma unroll
  for (int r = 0; r < 4; ++r) {
    const int row = base + w * 16 + lg * 4 + r;
    if (row < n) {
      const float dg = (float)(deg[row] + 1);
#pragma unroll
      for (int ct = 0; ct < 4; ++ct) {
        const int col = ct * 16 + l15;
        float v = acc[ct][r] + bu[col] + dg * dvec[col];
        v = v > 0.f ? v : 0.f;
        if (OUT_F32)
          ((float*)outp)[(size_t)row * 64 + col] = v;
        else
          ((unsigned short*)outp)[(size_t)row * 64 + col] = __half_as_ushort(__float2half(v));
      }
    }
  }
}

extern "C" void kernel_launch(void* const* d_in, const int* in_sizes, int n_in,
                              void* d_out, int out_size, void* d_ws, size_t ws_size,
                              hipStream_t stream) {
  const float* x = (const float*)d_in[0];
  const int* ei = (const int*)d_in[1];
  const int n = in_sizes[0] / DIM;   // 50000
  const int E = in_sizes[1] / 2;     // 800000
  const int* srcp = ei;
  const int* dstp = ei + E;
  const int nb = (n + 255) / 256;

  // Workspace layout (16B alignment maintained; E even)
  unsigned short* xb = (unsigned short*)d_ws;        // n*64 fp16
  unsigned short* hxb = xb + (size_t)n * DIM;        // n*64 fp16
  unsigned short* yb = hxb + (size_t)n * DIM;        // n*64 fp16
  unsigned short* Wtb = yb + (size_t)n * DIM;        // 3*8192 fp16
  unsigned short* csr16 = Wtb + 3 * 8192;            // E ushort
  float* dv = (float*)(csr16 + E);                   // 3*64
  int* deg = (int*)(dv + 3 * 64);                    // n
  int* cursor = deg + n;                             // n
  int* rowptr = cursor + n;                          // n+1
  int* bsum = rowptr + n + 1;                        // 256
  int* boff = bsum + 256;                            // 256

  // One-time prep: fused fp16 weights; fp16 x + degree (merged); CSR build.
  fuse_weights_kernel<<<3, 256, 0, stream>>>(
      (const float*)d_in[2], (const float*)d_in[3], (const float*)d_in[4],
      (const float*)d_in[6], (const float*)d_in[7], (const float*)d_in[8],
      (const float*)d_in[10], (const float*)d_in[11], (const float*)d_in[12],
      Wtb, dv);
  hipMemsetAsync(deg, 0, (size_t)n * sizeof(int), stream);
  const int nquads = n * DIM / 4;
  const int prep_n = nquads > E ? nquads : E;
  prep_kernel<<<(prep_n + 255) / 256, 256, 0, stream>>>(x, (unsigned*)xb, nquads, dstp, deg, E);
  scan_sum_kernel<<<nb, 256, 0, stream>>>(deg, bsum, n);
  scan_block_kernel<<<1, 256, 0, stream>>>(bsum, boff, nb);
  scan_write_kernel<<<nb, 256, 0, stream>>>(deg, boff, rowptr, cursor, n);
  fill_kernel<<<(E / 2 + 255) / 256, 256, 0, stream>>>(srcp, dstp, cursor, csr16, E / 2);

  // Layer chain (fp16): xb -> yb -> xb -> d_out(fp32)
  const int gblocks = (n + 63) / 64;
  gather_kernel<<<2048, 256, 0, stream>>>((const unsigned*)xb, rowptr, csr16, (unsigned*)hxb, n);
  gemm_kernel<0><<<gblocks, 256, 0, stream>>>(hxb, xb, Wtb, (const float*)d_in[5], dv, deg, yb, n);
  gather_kernel<<<2048, 256, 0, stream>>>((const unsigned*)yb, rowptr, csr16, (unsigned*)hxb, n);
  gemm_kernel<0><<<gblocks, 256, 0, stream>>>(hxb, yb, Wtb + 8192, (const float*)d_in[9], dv + 64, deg, xb, n);
  gather_kernel<<<2048, 256, 0, stream>>>((const unsigned*)xb, rowptr, csr16, (unsigned*)hxb, n);
  gemm_kernel<1><<<gblocks, 256, 0, stream>>>(hxb, xb, Wtb + 16384, (const float*)d_in[13], dv + 128, deg, d_out, n);
}

// Round 8
// 201.473 us; speedup vs baseline: 4.2782x; 1.0071x over previous
//
#include <hip/hip_runtime.h>
#include <hip/hip_fp16.h>

// MPNN, 3 layers, N=50000, E=800000, D=64.
//   hx[d] = x[d] + sum_{e: dst=d} x[src_e]            (CSR gather, fp16 data, fp32 accum)
//   out   = relu([hx | x] @ Wt^T + bu + (deg+1)*dvec) (fp16 MFMA, fp32 accum)
// Wt[n][k] = k<64 ? (Wm@Wu_top)[k][n] : Wu_bot[k-64][n]   (fp16, precomputed)
//
// Learned constraints:
//  - NO min-waves launch bound on register-heavy kernels (r4: spilled to scratch).
//  - MFMA A/B share the (g=lane>>4, j) -> k map: feeding both with f(g,j)=8g+j
//    (contiguous 16B loads) computes exact A*B. C/D: col=lane&15, row=4*(lane>>4)+reg.
//  - LDS A-tile rows stride 128B = same-bank; XOR-swizzle chunk^=(row&7).
//  - Scattered small stores to a small shared region ping-pong lines across the
//    8 non-coherent per-XCD L2s -> 25x HBM write amplification (r6/r7). Fix:
//    partition the destination range by (blockIdx & 7) so each XCD owns a slice.
//  - hipMemsetAsync of ~200KB costs 43us via rocclr fillBuffer (r7) -> zero it
//    ourselves from spare blocks of an existing kernel.

#define DIM 64

typedef _Float16 f16x8 __attribute__((ext_vector_type(8)));
typedef float f32x4 __attribute__((ext_vector_type(4)));

static __device__ __forceinline__ float lo16(unsigned u) {
  return __half2float(__ushort_as_half((unsigned short)(u & 0xFFFFu)));
}
static __device__ __forceinline__ float hi16(unsigned u) {
  return __half2float(__ushort_as_half((unsigned short)(u >> 16)));
}
static __device__ __forceinline__ unsigned pack16(float a, float b) {
  return (unsigned)__half_as_ushort(__float2half(a)) |
         ((unsigned)__half_as_ushort(__float2half(b)) << 16);
}

// blocks 0..2: fused fp16 weights per layer.  blocks 3..: zero deg[].
__global__ __launch_bounds__(256) void fuse_weights_kernel(
    const float* __restrict__ Wm0, const float* __restrict__ bm0, const float* __restrict__ Wu0,
    const float* __restrict__ Wm1, const float* __restrict__ bm1, const float* __restrict__ Wu1,
    const float* __restrict__ Wm2, const float* __restrict__ bm2, const float* __restrict__ Wu2,
    unsigned short* __restrict__ Wtb, float* __restrict__ dv,
    int* __restrict__ deg, int n) {
  const int l = blockIdx.x;
  if (l >= 3) {
    // zero deg: (gridDim-3) blocks, int4 grid-stride
    const int nq = n >> 2;  // n % 4 == 0
    const int t0 = (l - 3) * 256 + threadIdx.x;
    const int stride = (gridDim.x - 3) * 256;
    int4* d4 = (int4*)deg;
    for (int i = t0; i < nq; i += stride) d4[i] = make_int4(0, 0, 0, 0);
    return;
  }
  const float* Wm = l == 0 ? Wm0 : l == 1 ? Wm1 : Wm2;
  const float* bm = l == 0 ? bm0 : l == 1 ? bm1 : bm2;
  const float* Wu = l == 0 ? Wu0 : l == 1 ? Wu1 : Wu2;
  __shared__ float sWm[4096];
  __shared__ float sWu[4096];   // top half of Wu (rows 0..63)
  __shared__ float sW1[4096];   // Wm @ Wu_top
  const int tid = threadIdx.x;
  for (int i = tid; i < 4096; i += 256) {
    sWm[i] = Wm[i];
    sWu[i] = Wu[i];
  }
  __syncthreads();
  for (int i = tid; i < 4096; i += 256) {
    const int r = i >> 6, c = i & 63;
    float acc = 0.f;
#pragma unroll
    for (int k = 0; k < 64; ++k) acc = fmaf(sWm[r * 64 + k], sWu[k * 64 + c], acc);
    sW1[i] = acc;
  }
  __syncthreads();
  unsigned short* Wl = Wtb + (size_t)l * 8192;
  for (int i = tid; i < 8192; i += 256) {
    const int ncol = i >> 7, k = i & 127;
    const float v = (k < 64) ? sW1[k * 64 + ncol] : Wu[k * 64 + ncol];
    Wl[i] = __half_as_ushort(__float2half(v));
  }
  if (tid < 64) {
    float acc = 0.f;
#pragma unroll
    for (int k = 0; k < 64; ++k) acc = fmaf(bm[k], sWu[k * 64 + tid], acc);
    dv[l * 64 + tid] = acc;
  }
}

// Merged: fp32->fp16 convert of x (quad i) + degree count (edge i). Both 800k.
__global__ __launch_bounds__(256) void prep_kernel(
    const float* __restrict__ x, unsigned* __restrict__ xb2, int nquads,
    const int* __restrict__ dst, int* __restrict__ deg, int E) {
  const int i = blockIdx.x * 256 + threadIdx.x;
  if (i < nquads) {
    const float4 v = ((const float4*)x)[i];
    xb2[2 * i] = pack16(v.x, v.y);
    xb2[2 * i + 1] = pack16(v.z, v.w);
  }
  if (i < E) atomicAdd(&deg[dst[i]], 1);
}

// 3-phase multi-block exclusive scan of deg -> rowptr (and cursor = rowptr copy)
__global__ __launch_bounds__(256) void scan_sum_kernel(const int* __restrict__ deg,
                                                       int* __restrict__ bsum, int n) {
  const int i = blockIdx.x * 256 + threadIdx.x;
  int v = (i < n) ? deg[i] : 0;
#pragma unroll
  for (int off = 1; off < 64; off <<= 1) v += __shfl_down(v, off, 64);
  __shared__ int ws[4];
  if ((threadIdx.x & 63) == 0) ws[threadIdx.x >> 6] = v;
  __syncthreads();
  if (threadIdx.x == 0) bsum[blockIdx.x] = ws[0] + ws[1] + ws[2] + ws[3];
}

__global__ __launch_bounds__(256) void scan_block_kernel(const int* __restrict__ bsum,
                                                         int* __restrict__ boff, int nb) {
  __shared__ int s[256];
  const int t = threadIdx.x;
  s[t] = (t < nb) ? bsum[t] : 0;
  __syncthreads();
  for (int off = 1; off < 256; off <<= 1) {
    const int v = (t >= off) ? s[t - off] : 0;
    __syncthreads();
    s[t] += v;
    __syncthreads();
  }
  if (t < nb) boff[t] = (t == 0) ? 0 : s[t - 1];
}

__global__ __launch_bounds__(256) void scan_write_kernel(
    const int* __restrict__ deg, const int* __restrict__ boff,
    int* __restrict__ rowptr, int* __restrict__ cursor, int n) {
  __shared__ int s[256];
  const int t = threadIdx.x;
  const int i = blockIdx.x * 256 + t;
  const int v = (i < n) ? deg[i] : 0;
  s[t] = v;
  __syncthreads();
  for (int off = 1; off < 256; off <<= 1) {
    const int u = (t >= off) ? s[t - off] : 0;
    __syncthreads();
    s[t] += u;
    __syncthreads();
  }
  if (i < n) {
    const int excl = boff[blockIdx.x] + s[t] - v;
    rowptr[i] = excl;
    cursor[i] = excl;
    if (i == n - 1) rowptr[n] = excl + v;
  }
}

// XCD-partitioned CSR fill: partition p = blockIdx & 7 owns nodes
// [p*nd8, p==7 ? n : (p+1)*nd8). Each partition's blocks scan the full edge
// list but commit only their own dst range -> csr/cursor lines stay in one
// XCD's L2 (write locality; see header). Correct regardless of the actual
// block->XCD mapping.
__global__ __launch_bounds__(256) void fill_kernel(
    const int* __restrict__ src, const int* __restrict__ dst,
    int* __restrict__ cursor, unsigned short* __restrict__ csr16,
    int Epairs, int n, int nd8) {
  const int part = blockIdx.x & 7;
  const int lo = part * nd8;
  const int hi = (part == 7) ? n : lo + nd8;
  const int t0 = (blockIdx.x >> 3) * 256 + threadIdx.x;
  const int stride = (gridDim.x >> 3) * 256;
  for (int t = t0; t < Epairs; t += stride) {
    const int2 d2 = ((const int2*)dst)[t];
    const int2 s2 = ((const int2*)src)[t];
    if (d2.x >= lo && d2.x < hi) {
      const int p0 = atomicAdd(&cursor[d2.x], 1);
      csr16[p0] = (unsigned short)s2.x;
    }
    if (d2.y >= lo && d2.y < hi) {
      const int p1 = atomicAdd(&cursor[d2.y], 1);
      csr16[p1] = (unsigned short)s2.y;
    }
  }
}

// One wave per node, fp16 rows. Each load instr fetches TWO neighbor rows:
// half-wave h (lane>>5) picks the neighbor, 32 lanes x uint = one 128B row.
__global__ __launch_bounds__(256, 8) void gather_kernel(
    const unsigned* __restrict__ xu,   // fp16 x, 2 cols per uint, 32 uints/row
    const int* __restrict__ rowptr, const unsigned short* __restrict__ csr16,
    unsigned* __restrict__ hxu, int n) {
  const int lane = threadIdx.x & 63;
  const int j = lane & 31;
  const int h = lane >> 5;
  const int wid = (blockIdx.x * 256 + threadIdx.x) >> 6;
  const int nwaves = (gridDim.x * 256) >> 6;
  for (int node = wid; node < n; node += nwaves) {
    const int nodeu = __builtin_amdgcn_readfirstlane(node);
    const int beg = rowptr[nodeu];
    const int end = rowptr[nodeu + 1];
    const int cnt = end - beg;
    int myi = 0;
    if (lane < cnt) myi = (int)csr16[beg + lane];
    const int c64 = cnt > 64 ? 64 : cnt;
    float a0 = 0.f, a1 = 0.f, b0 = 0.f, b1 = 0.f;
    int i = 0;
    for (; i + 7 < c64; i += 8) {  // 4 pair-steps, 4 outstanding loads
      const int sA = __builtin_amdgcn_readlane(myi, i);
      const int sB = __builtin_amdgcn_readlane(myi, i + 1);
      const int sC = __builtin_amdgcn_readlane(myi, i + 2);
      const int sD = __builtin_amdgcn_readlane(myi, i + 3);
      const int sE = __builtin_amdgcn_readlane(myi, i + 4);
      const int sF = __builtin_amdgcn_readlane(myi, i + 5);
      const int sG = __builtin_amdgcn_readlane(myi, i + 6);
      const int sH = __builtin_amdgcn_readlane(myi, i + 7);
      const unsigned u0 = xu[(unsigned)(h ? sB : sA) * 32 + j];
      const unsigned u1 = xu[(unsigned)(h ? sD : sC) * 32 + j];
      const unsigned u2 = xu[(unsigned)(h ? sF : sE) * 32 + j];
      const unsigned u3 = xu[(unsigned)(h ? sH : sG) * 32 + j];
      a0 += lo16(u0); a1 += hi16(u0);
      b0 += lo16(u1); b1 += hi16(u1);
      a0 += lo16(u2); a1 += hi16(u2);
      b0 += lo16(u3); b1 += hi16(u3);
    }
    for (; i + 1 < c64; i += 2) {
      const int sA = __builtin_amdgcn_readlane(myi, i);
      const int sB = __builtin_amdgcn_readlane(myi, i + 1);
      const unsigned u = xu[(unsigned)(h ? sB : sA) * 32 + j];
      a0 += lo16(u); a1 += hi16(u);
    }
    if (i < c64 && h == 0) {  // odd tail: low half only
      const int sA = __builtin_amdgcn_readlane(myi, i);
      const unsigned u = xu[(unsigned)sA * 32 + j];
      a0 += lo16(u); a1 += hi16(u);
    }
    for (int t = beg + 64; t < end; ++t) {  // deg>64: ~never
      if (h == 0) {
        const unsigned u = xu[(unsigned)csr16[t] * 32 + j];
        a0 += lo16(u); a1 += hi16(u);
      }
    }
    a0 += b0; a1 += b1;
    a0 += __shfl_xor(a0, 32, 64);
    a1 += __shfl_xor(a1, 32, 64);
    if (h == 0) {
      const unsigned us = xu[(unsigned)nodeu * 32 + j];  // self
      hxu[(unsigned)nodeu * 32 + j] = pack16(a0 + lo16(us), a1 + hi16(us));
    }
  }
}

// 64 rows per block (4 waves x 16). A = [hx | x] (K=128) staged in swizzled
// LDS; B = Wt[n][k] fragments loaded as contiguous 16B; 16 MFMAs per wave.
template <int OUT_F32>
__global__ __launch_bounds__(256) void gemm_kernel(
    const unsigned short* __restrict__ hxb, const unsigned short* __restrict__ xb,
    const unsigned short* __restrict__ Wtb, const float* __restrict__ bu,
    const float* __restrict__ dvec, const int* __restrict__ deg,
    void* __restrict__ outp, int n) {
  __shared__ unsigned short lhx[64 * 64];
  __shared__ unsigned short lx[64 * 64];
  const int tid = threadIdx.x;
  const int base = blockIdx.x * 64;
  {
    const uint4* ghx = (const uint4*)hxb;
    const uint4* gx = (const uint4*)xb;
    uint4* shx = (uint4*)lhx;
    uint4* sx = (uint4*)lx;
    for (int t = tid; t < 512; t += 256) {
      const int row = t >> 3, c = t & 7;
      const int grow = base + row;
      uint4 vh = make_uint4(0, 0, 0, 0), vx = make_uint4(0, 0, 0, 0);
      if (grow < n) {
        vh = ghx[(size_t)grow * 8 + c];
        vx = gx[(size_t)grow * 8 + c];
      }
      const int cs = c ^ (row & 7);
      shx[row * 8 + cs] = vh;
      sx[row * 8 + cs] = vx;
    }
  }
  const int lane = tid & 63;
  const int w = tid >> 6;
  const int l15 = lane & 15, lg = lane >> 4;
  f16x8 bfr[16];
#pragma unroll
  for (int ct = 0; ct < 4; ++ct)
#pragma unroll
    for (int kq = 0; kq < 4; ++kq)
      bfr[ct * 4 + kq] = *(const f16x8*)((const char*)Wtb + (ct * 16 + l15) * 256 + kq * 64 + lg * 16);
  __syncthreads();
  f32x4 acc[4] = {0, 0, 0, 0};
  const int rt = w * 16 + l15;
#pragma unroll
  for (int kq = 0; kq < 4; ++kq) {
    const unsigned short* mat = (kq < 2) ? lhx : lx;
    const int chunk = lg + 4 * (kq & 1);
    const int cs = chunk ^ (rt & 7);
    const f16x8 af = *(const f16x8*)((const char*)mat + rt * 128 + cs * 16);
#pragma unroll
    for (int ct = 0; ct < 4; ++ct)
      acc[ct] = __builtin_amdgcn_mfma_f32_16x16x32_f16(af, bfr[ct * 4 + kq], acc[ct], 0, 0, 0);
  }
#pragma unroll
  for (int r = 0; r < 4; ++r) {
    const int row = base + w * 16 + lg * 4 + r;
    if (row < n) {
      const float dg = (float)(deg[row] + 1);
#pragma unroll
      for (int ct = 0; ct < 4; ++ct) {
        const int col = ct * 16 + l15;
        float v = acc[ct][r] + bu[col] + dg * dvec[col];
        v = v > 0.f ? v : 0.f;
        if (OUT_F32)
          ((float*)outp)[(size_t)row * 64 + col] = v;
        else
          ((unsigned short*)outp)[(size_t)row * 64 + col] = __half_as_ushort(__float2half(v));
      }
    }
  }
}

extern "C" void kernel_launch(void* const* d_in, const int* in_sizes, int n_in,
                              void* d_out, int out_size, void* d_ws, size_t ws_size,
                              hipStream_t stream) {
  const float* x = (const float*)d_in[0];
  const int* ei = (const int*)d_in[1];
  const int n = in_sizes[0] / DIM;   // 50000
  const int E = in_sizes[1] / 2;     // 800000
  const int* srcp = ei;
  const int* dstp = ei + E;
  const int nb = (n + 255) / 256;

  // Workspace layout (16B alignment maintained; E even)
  unsigned short* xb = (unsigned short*)d_ws;        // n*64 fp16
  unsigned short* hxb = xb + (size_t)n * DIM;        // n*64 fp16
  unsigned short* yb = hxb + (size_t)n * DIM;        // n*64 fp16
  unsigned short* Wtb = yb + (size_t)n * DIM;        // 3*8192 fp16
  unsigned short* csr16 = Wtb + 3 * 8192;            // E ushort
  float* dv = (float*)(csr16 + E);                   // 3*64
  int* deg = (int*)(dv + 3 * 64);                    // n
  int* cursor = deg + n;                             // n
  int* rowptr = cursor + n;                          // n+1
  int* bsum = rowptr + n + 1;                        // 256
  int* boff = bsum + 256;                            // 256

  // One-time prep: fused fp16 weights + deg zeroing (spare blocks); fp16 x +
  // degree (merged); CSR build (XCD-partitioned fill).
  fuse_weights_kernel<<<32, 256, 0, stream>>>(
      (const float*)d_in[2], (const float*)d_in[3], (const float*)d_in[4],
      (const float*)d_in[6], (const float*)d_in[7], (const float*)d_in[8],
      (const float*)d_in[10], (const float*)d_in[11], (const float*)d_in[12],
      Wtb, dv, deg, n);
  const int nquads = n * DIM / 4;
  const int prep_n = nquads > E ? nquads : E;
  prep_kernel<<<(prep_n + 255) / 256, 256, 0, stream>>>(x, (unsigned*)xb, nquads, dstp, deg, E);
  scan_sum_kernel<<<nb, 256, 0, stream>>>(deg, bsum, n);
  scan_block_kernel<<<1, 256, 0, stream>>>(bsum, boff, nb);
  scan_write_kernel<<<nb, 256, 0, stream>>>(deg, boff, rowptr, cursor, n);
  fill_kernel<<<512, 256, 0, stream>>>(srcp, dstp, cursor, csr16, E / 2, n, n / 8);

  // Layer chain (fp16): xb -> yb -> xb -> d_out(fp32)
  const int gblocks = (n + 63) / 64;
  gather_kernel<<<2048, 256, 0, stream>>>((const unsigned*)xb, rowptr, csr16, (unsigned*)hxb, n);
  gemm_kernel<0><<<gblocks, 256, 0, stream>>>(hxb, xb, Wtb, (const float*)d_in[5], dv, deg, yb, n);
  gather_kernel<<<2048, 256, 0, stream>>>((const unsigned*)yb, rowptr, csr16, (unsigned*)hxb, n);
  gemm_kernel<0><<<gblocks, 256, 0, stream>>>(hxb, yb, Wtb + 8192, (const float*)d_in[9], dv + 64, deg, xb, n);
  gather_kernel<<<2048, 256, 0, stream>>>((const unsigned*)xb, rowptr, csr16, (unsigned*)hxb, n);
  gemm_kernel<1><<<gblocks, 256, 0, stream>>>(hxb, xb, Wtb + 16384, (const float*)d_in[13], dv + 128, deg, d_out, n);
}